// Round 9
// baseline (557.678 us; speedup 1.0000x reference)
//
#include <hip/hip_runtime.h>
#include <hip/hip_bf16.h>

#define BB 2
#define TT 2048
#define DD 1024
#define NH 16
#define HALF 1024
#define DHID 4096
#define ND9 9216
#define ROWS (BB*TT)

using bf16 = __hip_bfloat16;
typedef short bf16x8 __attribute__((ext_vector_type(8)));
typedef float f32x4 __attribute__((ext_vector_type(4)));
typedef unsigned short u16;

__device__ __forceinline__ float bits2f(u16 b){ return __uint_as_float(((unsigned)b) << 16); }
__device__ __forceinline__ u16 fb(float v){              // float -> bf16 bits (RNE, bit-twiddle)
    unsigned u = __float_as_uint(v);
    u += 0x7fffu + ((u >> 16) & 1u);
    return (u16)(u >> 16);
}
__device__ __forceinline__ u16 fbh(float v){             // via cast: compiler fuses pairs to v_cvt_pk_bf16_f32
    bf16 b = __float2bfloat16(v);
    return *(u16*)&b;
}
__device__ __forceinline__ float fexp2(float x){
#if __has_builtin(__builtin_amdgcn_exp2f)
    return __builtin_amdgcn_exp2f(x);
#else
    return exp2f(x);
#endif
}
__device__ __forceinline__ void gl_lds16(const u16* g, u16* l) {
    __builtin_amdgcn_global_load_lds(
        (const __attribute__((address_space(1))) unsigned int*)g,
        (__attribute__((address_space(3))) unsigned int*)l, 16, 0, 0);
}
// XCD-chunked bijective block remap (T1): blocks sharing an operand panel land on one XCD.
// Requires nwg % 8 == 0 (all GEMM grids here satisfy this).
__device__ __forceinline__ void xcd_swz(int& bx, int& by) {
    int gx = gridDim.x;
    int nwg = gx * gridDim.y;
    int flat = blockIdx.y * gx + blockIdx.x;
    int swz = (flat & 7) * (nwg >> 3) + (flat >> 3);
    bx = swz % gx;
    by = swz / gx;
}

// ---------------- ada stage 1: partial[s][r][n] over 64-k slices ----------------
__global__ void ada_part(const float* __restrict__ c, const float* __restrict__ ada_w,
                         float* __restrict__ part) {
    __shared__ float sc_[4][64];
    int s = blockIdx.y;
    int k0 = s * 64;
    int n0 = blockIdx.x * 1024 + threadIdx.x * 4;
    {
        int r = threadIdx.x >> 6, k = threadIdx.x & 63;
        float v = c[r*DD + k0 + k];
        sc_[r][k] = v / (1.f + __expf(-v));
    }
    __syncthreads();
    float4 a0 = {0,0,0,0}, a1 = {0,0,0,0}, a2 = {0,0,0,0}, a3 = {0,0,0,0};
    for (int k = 0; k < 64; ++k) {
        float4 wv = *(const float4*)&ada_w[(size_t)(k0 + k)*ND9 + n0];
        float s0 = sc_[0][k], s1 = sc_[1][k], s2 = sc_[2][k], s3 = sc_[3][k];
        a0.x += s0*wv.x; a0.y += s0*wv.y; a0.z += s0*wv.z; a0.w += s0*wv.w;
        a1.x += s1*wv.x; a1.y += s1*wv.y; a1.z += s1*wv.z; a1.w += s1*wv.w;
        a2.x += s2*wv.x; a2.y += s2*wv.y; a2.z += s2*wv.z; a2.w += s2*wv.w;
        a3.x += s3*wv.x; a3.y += s3*wv.y; a3.z += s3*wv.z; a3.w += s3*wv.w;
    }
    *(float4*)&part[((size_t)(s*4 + 0))*ND9 + n0] = a0;
    *(float4*)&part[((size_t)(s*4 + 1))*ND9 + n0] = a1;
    *(float4*)&part[((size_t)(s*4 + 2))*ND9 + n0] = a2;
    *(float4*)&part[((size_t)(s*4 + 3))*ND9 + n0] = a3;
}

// ---------------- ada stage 2 ----------------
__global__ void ada_reduce(const float* __restrict__ part, const float* __restrict__ ada_b,
                           float* __restrict__ mod) {
    int g = blockIdx.x * 1024 + threadIdx.x * 4;
    int r = g / ND9, n = g - r*ND9;
    float4 acc = *(const float4*)&ada_b[n];
    #pragma unroll
    for (int s = 0; s < 16; ++s) {
        float4 p = *(const float4*)&part[((size_t)(s*4 + r))*ND9 + n];
        acc.x += p.x; acc.y += p.y; acc.z += p.z; acc.w += p.w;
    }
    *(float4*)&mod[(size_t)r*ND9 + n] = acc;
}

// ---------------- fused: xn = src (+ gv); [dstf = xn]; y = mod(ln(xn)) ----------------
__global__ void resid_ln(const float* __restrict__ src, const u16* __restrict__ gv,
                         const float* __restrict__ mod, int jshift, int jscale,
                         float* __restrict__ dstf, bf16* __restrict__ y) {
    int row = blockIdx.x;
    int b = row / TT, t = row % TT;
    int cz = (t >= HALF) ? 1 : 0;
    const float* mp = mod + (size_t)(b*2 + cz) * ND9;
    int tid = threadIdx.x;
    int w = tid >> 6, lane = tid & 63;
    int d0 = tid * 4;
    float4 s = *(const float4*)&src[(size_t)row*DD + d0];
    float v[4] = {s.x, s.y, s.z, s.w};
    if (gv) {
        ushort4 g = *(const ushort4*)&gv[(size_t)row*DD + d0];
        v[0] += bits2f(g.x); v[1] += bits2f(g.y); v[2] += bits2f(g.z); v[3] += bits2f(g.w);
    }
    if (dstf) *(float4*)&dstf[(size_t)row*DD + d0] = (float4){v[0], v[1], v[2], v[3]};
    float sum = v[0]+v[1]+v[2]+v[3];
    float ssq = v[0]*v[0]+v[1]*v[1]+v[2]*v[2]+v[3]*v[3];
    #pragma unroll
    for (int o = 32; o > 0; o >>= 1) {
        sum += __shfl_down(sum, o);
        ssq += __shfl_down(ssq, o);
    }
    __shared__ float wsum[4], wssq[4];
    if (lane == 0) { wsum[w] = sum; wssq[w] = ssq; }
    __syncthreads();
    float sall = (wsum[0]+wsum[1]) + (wsum[2]+wsum[3]);
    float qall = (wssq[0]+wssq[1]) + (wssq[2]+wssq[3]);
    float mean = sall * (1.f/DD);
    float var = qall * (1.f/DD) - mean*mean;
    float rstd = rsqrtf(var + 1e-6f);
    float4 sh = *(const float4*)&mp[jshift*DD + d0];
    float4 sc = *(const float4*)&mp[jscale*DD + d0];
    ushort4 o4;
    o4.x = fb((v[0]-mean)*rstd*(1.f+sc.x) + sh.x);
    o4.y = fb((v[1]-mean)*rstd*(1.f+sc.y) + sh.y);
    o4.z = fb((v[2]-mean)*rstd*(1.f+sc.z) + sh.z);
    o4.w = fb((v[3]-mean)*rstd*(1.f+sc.w) + sh.w);
    *(ushort4*)((u16*)y + (size_t)row*DD + d0) = o4;
}

// ---------------- W (KxN f32) -> Wt (NxK bf16 bits) ----------------
__global__ void transpose_w(const float* __restrict__ W, u16* __restrict__ Wt, int K, int N) {
    __shared__ float T[32][33];
    int n0 = blockIdx.x * 32, k0 = blockIdx.y * 32;
    int lx = threadIdx.x & 31, ly = threadIdx.x >> 5;
    #pragma unroll
    for (int i = 0; i < 4; ++i)
        T[ly + i*8][lx] = W[(size_t)(k0 + ly + i*8)*N + n0 + lx];
    __syncthreads();
    #pragma unroll
    for (int i = 0; i < 4; ++i) {
        int n = ly + i*8;
        Wt[(size_t)(n0 + n)*K + k0 + lx] = fb(T[lx][n]);
    }
}

// ---------------- V slice of qkv -> vt[bh*16+head][d][key] ----------------
__global__ void vtrans(const u16* __restrict__ qkv, u16* __restrict__ vt) {
    __shared__ u16 T[64][72];
    int kt = blockIdx.y;
    int gh = blockIdx.x;
    int tid = threadIdx.x;
    int key = tid >> 2, c8 = (tid & 3) * 16;
    const u16* src = qkv + (size_t)((gh >> 4)*1024 + kt*64 + key)*3072 + 2048 + (gh & 15)*64 + c8;
    *(uint4*)&T[key][c8]     = *(const uint4*)src;
    *(uint4*)&T[key][c8 + 8] = *(const uint4*)(src + 8);
    __syncthreads();
    int d = tid >> 2, kc = (tid & 3) * 16;
    u16 tmp[16];
    #pragma unroll
    for (int i = 0; i < 16; ++i) tmp[i] = T[kc + i][d];
    u16* dst = vt + ((size_t)gh*64 + d)*1024 + kt*64 + kc;
    *(uint4*)&dst[0] = *(const uint4*)&tmp[0];
    *(uint4*)&dst[8] = *(const uint4*)&tmp[8];
}

// ---------------- epilogue helper ----------------
// epi 0: plain bf16   epi 1: gelu bf16   epi 3: mod-gate bf16   epi 4: mod-gate + f32 residual add (in place)
__device__ __forceinline__ void epi_store(u16* out, int N, int mm, int n, float v,
                                          const float* mod, int jg, int epi) {
    if (epi == 0) {
        out[(size_t)mm*N + n] = fb(v);
    } else if (epi == 1) {
        float z = 0.7978845608028654f*(v + 0.044715f*v*v*v);
        out[(size_t)mm*N + n] = fb(v / (1.f + __expf(-2.f*z)));
    } else {
        int brow = mm / TT, tt2 = mm % TT;
        int cz = (tt2 >= HALF) ? 1 : 0;
        const float* mp = mod + (size_t)(brow*2 + cz)*ND9 + (size_t)jg*DD;
        if (epi == 3) {
            out[(size_t)mm*N + n] = fb(mp[n]*v);
        } else {
            float* of = (float*)out;
            size_t idx = (size_t)mm*N + n;
            of[idx] += mp[n]*v;
        }
    }
}

// ---------------- MFMA GEMM 128x128 tile, BK=64, swizzled LDS + XCD swizzle ----------------
__global__ __launch_bounds__(256, 2) void gemm_mfma(
    const u16* __restrict__ A, const u16* __restrict__ Wt, const float* __restrict__ bias,
    u16* __restrict__ out, const float* __restrict__ mod, int jg,
    int K, int N, int epi)
{
    __shared__ u16 As[128*64];
    __shared__ u16 Bs[128*64];
    int tid = threadIdx.x;
    int w = tid >> 6, lane = tid & 63;
    int quad = lane >> 4, l16 = lane & 15;
    int bx, by; xcd_swz(bx, by);
    int m0 = by * 128;
    int n0 = bx * 128;
    int wr = (w & 1) * 64, wc = (w >> 1) * 64;

    f32x4 acc[4][4];
    #pragma unroll
    for (int i = 0; i < 4; ++i)
        #pragma unroll
        for (int j = 0; j < 4; ++j) acc[i][j] = (f32x4){0.f,0.f,0.f,0.f};

    const u16* Ag = A + (size_t)m0 * K;
    const u16* Bg = Wt + (size_t)n0 * K;
    int srow = lane >> 3;
    int scol = (((lane & 7) ^ ((lane >> 3) & 7))) * 8;
    int xsw = (l16 & 7);

    for (int k0 = 0; k0 < K; k0 += 64) {
        #pragma unroll
        for (int c = 0; c < 4; ++c) {
            int ch = w*4 + c;
            gl_lds16(Ag + (size_t)(ch*8 + srow)*K + k0 + scol, As + ch*512);
            gl_lds16(Bg + (size_t)(ch*8 + srow)*K + k0 + scol, Bs + ch*512);
        }
        __syncthreads();
        #pragma unroll
        for (int kk = 0; kk < 2; ++kk) {
            int pc = ((kk*4 + quad) ^ xsw) * 8;
            bf16x8 af[4], bfr[4];
            #pragma unroll
            for (int i = 0; i < 4; ++i) af[i] = *(const bf16x8*)&As[(wr + i*16 + l16)*64 + pc];
            #pragma unroll
            for (int j = 0; j < 4; ++j) bfr[j] = *(const bf16x8*)&Bs[(wc + j*16 + l16)*64 + pc];
            #pragma unroll
            for (int i = 0; i < 4; ++i)
                #pragma unroll
                for (int j = 0; j < 4; ++j)
                    acc[i][j] = __builtin_amdgcn_mfma_f32_16x16x32_bf16(af[i], bfr[j], acc[i][j], 0, 0, 0);
        }
        __syncthreads();
    }

    #pragma unroll
    for (int i = 0; i < 4; ++i)
        #pragma unroll
        for (int r = 0; r < 4; ++r) {
            int mm = m0 + wr + i*16 + quad*4 + r;
            #pragma unroll
            for (int j = 0; j < 4; ++j) {
                int n = n0 + wc + j*16 + l16;
                epi_store(out, N, mm, n, acc[i][j][r] + bias[n], mod, jg, epi);
            }
        }
}

// ---------------- MFMA GEMM 128x64 tile (M x N), BK=64, single-buffered, high co-residency --
// Occupancy lever (m97 mechanism): 24 KB LDS + narrow N-tile -> 4-6 blocks/CU co-resident;
// implicit wave-level overlap hides staging latency (m114). Wave-tile 64x32 (ratio 21 FLOP/B).
__global__ __launch_bounds__(256, 4) void gemm128x64(
    const u16* __restrict__ A, const u16* __restrict__ Wt, const float* __restrict__ bias,
    u16* __restrict__ out, const float* __restrict__ mod, int jg,
    int K, int N, int epi)
{
    __shared__ u16 As[128*64];   // 16 KB
    __shared__ u16 Bs[64*64];    // 8 KB
    int tid = threadIdx.x;
    int w = tid >> 6, lane = tid & 63;
    int quad = lane >> 4, l16 = lane & 15;
    int bx, by; xcd_swz(bx, by);
    int m0 = by * 128;
    int n0 = bx * 64;
    int wr = (w & 1) * 64;       // 2-way M split
    int wc = (w >> 1) * 32;      // 2-way N split

    f32x4 acc[4][2];
    #pragma unroll
    for (int i = 0; i < 4; ++i)
        #pragma unroll
        for (int j = 0; j < 2; ++j) acc[i][j] = (f32x4){0.f,0.f,0.f,0.f};

    const u16* Ag = A + (size_t)m0 * K;
    const u16* Bg = Wt + (size_t)n0 * K;
    int srow = lane >> 3;
    int scol = (((lane & 7) ^ ((lane >> 3) & 7))) * 8;
    int xsw = (l16 & 7);

    for (int k0 = 0; k0 < K; k0 += 64) {
        #pragma unroll
        for (int c = 0; c < 4; ++c) {               // A: 16 chunks of 8 rows, 4/wave
            int ch = w*4 + c;
            gl_lds16(Ag + (size_t)(ch*8 + srow)*K + k0 + scol, As + ch*512);
        }
        #pragma unroll
        for (int c = 0; c < 2; ++c) {               // B: 8 chunks, 2/wave
            int ch = w*2 + c;
            gl_lds16(Bg + (size_t)(ch*8 + srow)*K + k0 + scol, Bs + ch*512);
        }
        __syncthreads();
        #pragma unroll
        for (int kk = 0; kk < 2; ++kk) {
            int pc = ((kk*4 + quad) ^ xsw) * 8;
            bf16x8 af[4], bfr[2];
            #pragma unroll
            for (int i = 0; i < 4; ++i) af[i] = *(const bf16x8*)&As[(wr + i*16 + l16)*64 + pc];
            #pragma unroll
            for (int j = 0; j < 2; ++j) bfr[j] = *(const bf16x8*)&Bs[(wc + j*16 + l16)*64 + pc];
            #pragma unroll
            for (int i = 0; i < 4; ++i)
                #pragma unroll
                for (int j = 0; j < 2; ++j)
                    acc[i][j] = __builtin_amdgcn_mfma_f32_16x16x32_bf16(af[i], bfr[j], acc[i][j], 0, 0, 0);
        }
        __syncthreads();
    }

    #pragma unroll
    for (int i = 0; i < 4; ++i)
        #pragma unroll
        for (int r = 0; r < 4; ++r) {
            int mm = m0 + wr + i*16 + quad*4 + r;
            #pragma unroll
            for (int j = 0; j < 2; ++j) {
                int n = n0 + wc + j*16 + l16;
                epi_store(out, N, mm, n, acc[i][j][r] + bias[n], mod, jg, epi);
            }
        }
}

// ---------------- MFMA GEMM 64x128 tile, BK=128 + XCD swizzle (projs control) ----------------
__global__ __launch_bounds__(256, 2) void gemm64_k128(
    const u16* __restrict__ A, const u16* __restrict__ Wt, const float* __restrict__ bias,
    u16* __restrict__ out, const float* __restrict__ mod, int jg,
    int K, int N, int epi)
{
    __shared__ u16 As[2*64*64];      // 16 KB: [half][row][64]
    __shared__ u16 Bs[2*128*64];     // 32 KB
    int tid = threadIdx.x;
    int w = tid >> 6, lane = tid & 63;
    int quad = lane >> 4, l16 = lane & 15;
    int bx, by; xcd_swz(bx, by);
    int m0 = by * 64;
    int n0 = bx * 128;

    f32x4 acc[4][2];
    #pragma unroll
    for (int i = 0; i < 4; ++i)
        #pragma unroll
        for (int j = 0; j < 2; ++j) acc[i][j] = (f32x4){0.f,0.f,0.f,0.f};

    const u16* Ag = A + (size_t)m0 * K;
    const u16* Bg = Wt + (size_t)n0 * K;
    int srow = lane >> 3;
    int scol = (((lane & 7) ^ ((lane >> 3) & 7))) * 8;
    int xsw = (l16 & 7);

    for (int k0 = 0; k0 < K; k0 += 128) {
        #pragma unroll
        for (int h = 0; h < 2; ++h) {
            #pragma unroll
            for (int c = 0; c < 2; ++c) {
                int ch = w*2 + c;
                gl_lds16(Ag + (size_t)(ch*8 + srow)*K + k0 + h*64 + scol, As + h*4096 + ch*512);
            }
            #pragma unroll
            for (int c = 0; c < 4; ++c) {
                int ch = w*4 + c;
                gl_lds16(Bg + (size_t)(ch*8 + srow)*K + k0 + h*64 + scol, Bs + h*8192 + ch*512);
            }
        }
        __syncthreads();
        #pragma unroll
        for (int kk = 0; kk < 4; ++kk) {
            int hh = kk >> 1;
            int pc = (((kk & 1)*4 + quad) ^ xsw) * 8;
            bf16x8 af[4], bfr[2];
            #pragma unroll
            for (int i = 0; i < 4; ++i) af[i] = *(const bf16x8*)&As[hh*4096 + (i*16 + l16)*64 + pc];
            #pragma unroll
            for (int j = 0; j < 2; ++j) bfr[j] = *(const bf16x8*)&Bs[hh*8192 + (w*32 + j*16 + l16)*64 + pc];
            #pragma unroll
            for (int i = 0; i < 4; ++i)
                #pragma unroll
                for (int j = 0; j < 2; ++j)
                    acc[i][j] = __builtin_amdgcn_mfma_f32_16x16x32_bf16(af[i], bfr[j], acc[i][j], 0, 0, 0);
        }
        __syncthreads();
    }

    #pragma unroll
    for (int i = 0; i < 4; ++i)
        #pragma unroll
        for (int r = 0; r < 4; ++r) {
            int mm = m0 + i*16 + quad*4 + r;
            #pragma unroll
            for (int j = 0; j < 2; ++j) {
                int n = n0 + w*32 + j*16 + l16;
                epi_store(out, N, mm, n, acc[i][j][r] + bias[n], mod, jg, epi);
            }
        }
}

// ---------------- MFMA flash attention (S^T trick, staged K/V, reg-prefetch) ----------------
__global__ __launch_bounds__(256) void attn_mfma(const u16* __restrict__ qkv,
                                                 const u16* __restrict__ vt,
                                                 u16* __restrict__ attn_out, int kv_swap) {
    __shared__ u16 Ks[64][72];       // [key][d]
    __shared__ u16 Vs[64][72];       // [d][key]
    __shared__ u16 Ps[4][16][72];    // per-wave P: [q=l16][key]
    int head = blockIdx.x, qt = blockIdx.y, bh = blockIdx.z;
    int kvbh = kv_swap ? (bh ^ 1) : bh;
    int tid = threadIdx.x;
    int w = tid >> 6, lane = tid & 63;
    int quad = lane >> 4, l16 = lane & 15;
    int qrow0 = bh*1024 + qt*64 + w*16;

    const u16* qp = qkv + (size_t)(qrow0 + l16)*3072 + head*64;
    bf16x8 qa0 = *(const bf16x8*)(qp + quad*8);        // Q[q=l16][d=quad*8+j]
    bf16x8 qa1 = *(const bf16x8*)(qp + 32 + quad*8);

    f32x4 oacc[4];
    #pragma unroll
    for (int i = 0; i < 4; ++i) oacc[i] = (f32x4){0.f,0.f,0.f,0.f};
    float mst = -3e38f, lst = 0.f;                     // running max (log2 domain) / denom per q

    int skey = tid >> 2, sc8 = (tid & 3) * 16;
    const u16* kbase = qkv + (size_t)(kvbh*1024 + skey)*3072 + 1024 + head*64 + sc8;
    const u16* vbase = vt + ((size_t)(kvbh*16 + head)*64 + skey)*1024 + sc8;

    uint4 kr0 = *(const uint4*)kbase;
    uint4 kr1 = *(const uint4*)(kbase + 8);
    uint4 vr0 = *(const uint4*)vbase;
    uint4 vr1 = *(const uint4*)(vbase + 8);

    const float SSC = 0.125f * 1.4426950408889634f;    // head-dim scale * log2(e)
    for (int kt = 0; kt < 16; ++kt) {
        __syncthreads();                               // previous tile fully consumed
        *(uint4*)&Ks[skey][sc8]     = kr0;
        *(uint4*)&Ks[skey][sc8 + 8] = kr1;
        *(uint4*)&Vs[skey][sc8]     = vr0;
        *(uint4*)&Vs[skey][sc8 + 8] = vr1;
        __syncthreads();
        if (kt < 15) {                                 // prefetch next tile into regs (hides under MFMA)
            const u16* kp = kbase + (size_t)(kt + 1)*64*3072;
            kr0 = *(const uint4*)kp;
            kr1 = *(const uint4*)(kp + 8);
            const u16* vp = vbase + (kt + 1)*64;
            vr0 = *(const uint4*)vp;
            vr1 = *(const uint4*)(vp + 8);
        }

        // S^T[key][q] = K·Q^T
        f32x4 sacc[4];
        #pragma unroll
        for (int nt = 0; nt < 4; ++nt) sacc[nt] = (f32x4){0.f,0.f,0.f,0.f};
        __builtin_amdgcn_s_setprio(1);
        #pragma unroll
        for (int nt = 0; nt < 4; ++nt) {
            bf16x8 kb0 = *(const bf16x8*)&Ks[nt*16 + l16][quad*8];
            bf16x8 kb1 = *(const bf16x8*)&Ks[nt*16 + l16][32 + quad*8];
            sacc[nt] = __builtin_amdgcn_mfma_f32_16x16x32_bf16(kb0, qa0, sacc[nt], 0, 0, 0);
            sacc[nt] = __builtin_amdgcn_mfma_f32_16x16x32_bf16(kb1, qa1, sacc[nt], 0, 0, 0);
        }
        __builtin_amdgcn_s_setprio(0);

        // softmax over keys (16 in-lane + cross-quad shfl) per q=l16, exp2 domain
        float sv[4][4];
        float tm = -3e38f;
        #pragma unroll
        for (int nt = 0; nt < 4; ++nt)
            #pragma unroll
            for (int r = 0; r < 4; ++r) {
                sv[nt][r] = sacc[nt][r] * SSC;
                tm = fmaxf(tm, sv[nt][r]);
            }
        tm = fmaxf(tm, __shfl_xor(tm, 16));
        tm = fmaxf(tm, __shfl_xor(tm, 32));
        if (!__all(tm <= mst + 11.5f)) {               // defer-max: rescale only on real growth
            float mnew = fmaxf(mst, tm);
            float alpha = fexp2(mst - mnew);
            lst *= alpha;
            #pragma unroll
            for (int dt = 0; dt < 4; ++dt)
                #pragma unroll
                for (int r = 0; r < 4; ++r) oacc[dt][r] *= alpha;
            mst = mnew;
        }
        float ls = 0.f;
        #pragma unroll
        for (int nt = 0; nt < 4; ++nt) {
            float p0 = fexp2(sv[nt][0] - mst), p1 = fexp2(sv[nt][1] - mst);
            float p2 = fexp2(sv[nt][2] - mst), p3 = fexp2(sv[nt][3] - mst);
            ls += (p0 + p1) + (p2 + p3);
            ushort4 pk = {fbh(p0), fbh(p1), fbh(p2), fbh(p3)};
            *(ushort4*)&Ps[w][l16][nt*16 + quad*4] = pk;
        }
        ls += __shfl_xor(ls, 16);
        ls += __shfl_xor(ls, 32);
        lst += ls;

        // O^T[d][q] += V^T·P^T
        bf16x8 pa0 = *(const bf16x8*)&Ps[w][l16][quad*8];
        bf16x8 pa1 = *(const bf16x8*)&Ps[w][l16][32 + quad*8];
        __builtin_amdgcn_s_setprio(1);
        #pragma unroll
        for (int dt = 0; dt < 4; ++dt) {
            bf16x8 vb0 = *(const bf16x8*)&Vs[dt*16 + l16][quad*8];
            bf16x8 vb1 = *(const bf16x8*)&Vs[dt*16 + l16][32 + quad*8];
            oacc[dt] = __builtin_amdgcn_mfma_f32_16x16x32_bf16(vb0, pa0, oacc[dt], 0, 0, 0);
            oacc[dt] = __builtin_amdgcn_mfma_f32_16x16x32_bf16(vb1, pa1, oacc[dt], 0, 0, 0);
        }
        __builtin_amdgcn_s_setprio(0);
    }
    float rl = 1.f / lst;
    #pragma unroll
    for (int dt = 0; dt < 4; ++dt) {
        ushort4 o4 = {fbh(oacc[dt][0]*rl), fbh(oacc[dt][1]*rl),
                      fbh(oacc[dt][2]*rl), fbh(oacc[dt][3]*rl)};
        *(ushort4*)&attn_out[(size_t)(qrow0 + l16)*DD + head*64 + dt*16 + quad*4] = o4;
    }
}

extern "C" void kernel_launch(void* const* d_in, const int* in_sizes, int n_in,
                              void* d_out, int out_size, void* d_ws, size_t ws_size,
                              hipStream_t stream) {
    const float* x          = (const float*)d_in[0];
    const float* c          = (const float*)d_in[1];
    const float* attn_qkv_w = (const float*)d_in[2];
    const float* attn_qkv_b = (const float*)d_in[3];
    const float* attn_proj_w= (const float*)d_in[4];
    const float* attn_proj_b= (const float*)d_in[5];
    const float* crs_qkv_w  = (const float*)d_in[6];
    const float* crs_qkv_b  = (const float*)d_in[7];
    const float* crs_proj_w = (const float*)d_in[8];
    const float* crs_proj_b = (const float*)d_in[9];
    const float* fc1_w      = (const float*)d_in[10];
    const float* fc1_b      = (const float*)d_in[11];
    const float* fc2_w      = (const float*)d_in[12];
    const float* fc2_b      = (const float*)d_in[13];
    const float* ada_w      = (const float*)d_in[14];
    const float* ada_b      = (const float*)d_in[15];
    float* out = (float*)d_out;     // f32 running residual

    // ws: mod 0.25 MB | R1 16 MB | Yr 8 MB | AOr 8 MB | BIGr 24 MB = 56.25 MB
    char* ws = (char*)d_ws;
    float* mod = (float*)ws;
    char* R1   = ws + (256u<<10);
    char* Yr   = R1 + (16u<<20);
    char* AOr  = Yr + (8u<<20);
    char* BIGr = AOr + (8u<<20);

    u16*   wt_a  = (u16*)R1;                   // 6 MB qkv weight T
    u16*   vt    = (u16*)(R1 + (8u<<20));      // 8 MB V-transpose
    bf16*  y     = (bf16*)Yr;                  // 8 MB ln output
    u16*   wt_p  = (u16*)Yr;                   // 2 MB proj weight T (y dead)
    u16*   attn_o= (u16*)AOr;                  // 8 MB
    u16*   big   = (u16*)BIGr;                 // 24 MB qkv
    u16*   gvB   = (u16*)BIGr;                 // 8 MB gated branch output (big dead)
    u16*   hstage= (u16*)AOr;                  // 32 MB fc1 out (AOr+BIGr contiguous)
    u16*   fc1_t = (u16*)R1;                   // 8 MB
    u16*   fc2_t = (u16*)(R1 + (8u<<20));      // 8 MB
    float* apart = (float*)BIGr;               // 2.4 MB ada partials (pre-MSA only)

    ada_part<<<dim3(9, 16), 256, 0, stream>>>(c, ada_w, apart);
    ada_reduce<<<36, 256, 0, stream>>>(apart, ada_b, mod);

    // ================= MSA =================
    transpose_w<<<dim3(3*DD/32, DD/32), 256, 0, stream>>>(attn_qkv_w, wt_a, DD, 3*DD);
    // fused x-copy: read x, write residual copy to out, produce y = mod(ln(x))
    resid_ln<<<ROWS, 256, 0, stream>>>(x, nullptr, mod, 0, 1, out, y);
    // qkv on 128x64 tiles: grid (48,32) = 1536 blocks = 6/CU co-resident
    gemm128x64<<<dim3(3*DD/64, ROWS/128), 256, 0, stream>>>((const u16*)y, wt_a, attn_qkv_b,
                                                            big, nullptr, 0, DD, 3*DD, 0);
    vtrans<<<dim3(64, 16), 256, 0, stream>>>(big, vt);
    attn_mfma<<<dim3(NH, 16, 4), 256, 0, stream>>>(big, vt, attn_o, 0);
    transpose_w<<<dim3(DD/32, DD/32), 256, 0, stream>>>(attn_proj_w, wt_p, DD, DD);
    gemm64_k128<<<dim3(DD/128, ROWS/64), 256, 0, stream>>>(attn_o, wt_p, attn_proj_b,
                                                           gvB, mod, 2, DD, DD, 3);
    // y = mod(ln(out + gvB)) for MCA; running residual (out) unchanged per reference
    resid_ln<<<ROWS, 256, 0, stream>>>(out, gvB, mod, 3, 4, nullptr, y);

    // ================= MCA =================
    transpose_w<<<dim3(3*DD/32, DD/32), 256, 0, stream>>>(crs_qkv_w, wt_a, DD, 3*DD);
    gemm128x64<<<dim3(3*DD/64, ROWS/128), 256, 0, stream>>>((const u16*)y, wt_a, crs_qkv_b,
                                                            big, nullptr, 0, DD, 3*DD, 0);
    vtrans<<<dim3(64, 16), 256, 0, stream>>>(big, vt);
    attn_mfma<<<dim3(NH, 16, 4), 256, 0, stream>>>(big, vt, attn_o, 1);
    transpose_w<<<dim3(DD/32, DD/32), 256, 0, stream>>>(crs_proj_w, wt_p, DD, DD);
    gemm64_k128<<<dim3(DD/128, ROWS/64), 256, 0, stream>>>(attn_o, wt_p, crs_proj_b,
                                                           gvB, mod, 5, DD, DD, 3);
    // out += gvB (store), y = mod(ln(out)) for MLP
    resid_ln<<<ROWS, 256, 0, stream>>>(out, gvB, mod, 6, 7, out, y);

    // ================= MLP =================
    transpose_w<<<dim3(DHID/32, DD/32), 256, 0, stream>>>(fc1_w, fc1_t, DD, DHID);
    transpose_w<<<dim3(DD/32, DHID/32), 256, 0, stream>>>(fc2_w, fc2_t, DHID, DD);
    gemm_mfma<<<dim3(DHID/128, ROWS/128), 256, 0, stream>>>((const u16*)y, fc1_t, fc1_b,
                                                            hstage, nullptr, 0, DD, DHID, 1);
    // fc2 on 128x64 tiles: grid (16,32) = 1024 blocks = 4/CU (vs 2 before)
    gemm128x64<<<dim3(DD/64, ROWS/128), 256, 0, stream>>>(hstage, fc2_t, fc2_b,
                                                          (u16*)out, mod, 8, DHID, DD, 4);
}

// Round 11
// 544.548 us; speedup vs baseline: 1.0241x; 1.0241x over previous
//
#include <hip/hip_runtime.h>
#include <hip/hip_bf16.h>

#define BB 2
#define TT 2048
#define DD 1024
#define NH 16
#define HALF 1024
#define DHID 4096
#define ND9 9216
#define ROWS (BB*TT)

using bf16 = __hip_bfloat16;
typedef short bf16x8 __attribute__((ext_vector_type(8)));
typedef float f32x4 __attribute__((ext_vector_type(4)));
typedef unsigned short u16;

__device__ __forceinline__ float bits2f(u16 b){ return __uint_as_float(((unsigned)b) << 16); }
__device__ __forceinline__ u16 fb(float v){              // float -> bf16 bits (RNE, bit-twiddle)
    unsigned u = __float_as_uint(v);
    u += 0x7fffu + ((u >> 16) & 1u);
    return (u16)(u >> 16);
}
__device__ __forceinline__ u16 fbh(float v){             // via cast: compiler fuses pairs to v_cvt_pk_bf16_f32
    bf16 b = __float2bfloat16(v);
    return *(u16*)&b;
}
__device__ __forceinline__ float fexp2(float x){
#if __has_builtin(__builtin_amdgcn_exp2f)
    return __builtin_amdgcn_exp2f(x);
#else
    return exp2f(x);
#endif
}
__device__ __forceinline__ void gl_lds16(const u16* g, u16* l) {
    __builtin_amdgcn_global_load_lds(
        (const __attribute__((address_space(1))) unsigned int*)g,
        (__attribute__((address_space(3))) unsigned int*)l, 16, 0, 0);
}
// XCD-chunked bijective block remap (T1): blocks sharing an operand panel land on one XCD.
// Requires nwg % 8 == 0 (all GEMM grids here satisfy this).
__device__ __forceinline__ void xcd_swz(int& bx, int& by) {
    int gx = gridDim.x;
    int nwg = gx * gridDim.y;
    int flat = blockIdx.y * gx + blockIdx.x;
    int swz = (flat & 7) * (nwg >> 3) + (flat >> 3);
    bx = swz % gx;
    by = swz / gx;
}

// ---------------- ada stage 1: partial[s][r][n] over 64-k slices ----------------
__global__ void ada_part(const float* __restrict__ c, const float* __restrict__ ada_w,
                         float* __restrict__ part) {
    __shared__ float sc_[4][64];
    int s = blockIdx.y;
    int k0 = s * 64;
    int n0 = blockIdx.x * 1024 + threadIdx.x * 4;
    {
        int r = threadIdx.x >> 6, k = threadIdx.x & 63;
        float v = c[r*DD + k0 + k];
        sc_[r][k] = v / (1.f + __expf(-v));
    }
    __syncthreads();
    float4 a0 = {0,0,0,0}, a1 = {0,0,0,0}, a2 = {0,0,0,0}, a3 = {0,0,0,0};
    for (int k = 0; k < 64; ++k) {
        float4 wv = *(const float4*)&ada_w[(size_t)(k0 + k)*ND9 + n0];
        float s0 = sc_[0][k], s1 = sc_[1][k], s2 = sc_[2][k], s3 = sc_[3][k];
        a0.x += s0*wv.x; a0.y += s0*wv.y; a0.z += s0*wv.z; a0.w += s0*wv.w;
        a1.x += s1*wv.x; a1.y += s1*wv.y; a1.z += s1*wv.z; a1.w += s1*wv.w;
        a2.x += s2*wv.x; a2.y += s2*wv.y; a2.z += s2*wv.z; a2.w += s2*wv.w;
        a3.x += s3*wv.x; a3.y += s3*wv.y; a3.z += s3*wv.z; a3.w += s3*wv.w;
    }
    *(float4*)&part[((size_t)(s*4 + 0))*ND9 + n0] = a0;
    *(float4*)&part[((size_t)(s*4 + 1))*ND9 + n0] = a1;
    *(float4*)&part[((size_t)(s*4 + 2))*ND9 + n0] = a2;
    *(float4*)&part[((size_t)(s*4 + 3))*ND9 + n0] = a3;
}

// ---------------- ada stage 2 ----------------
__global__ void ada_reduce(const float* __restrict__ part, const float* __restrict__ ada_b,
                           float* __restrict__ mod) {
    int g = blockIdx.x * 1024 + threadIdx.x * 4;
    int r = g / ND9, n = g - r*ND9;
    float4 acc = *(const float4*)&ada_b[n];
    #pragma unroll
    for (int s = 0; s < 16; ++s) {
        float4 p = *(const float4*)&part[((size_t)(s*4 + r))*ND9 + n];
        acc.x += p.x; acc.y += p.y; acc.z += p.z; acc.w += p.w;
    }
    *(float4*)&mod[(size_t)r*ND9 + n] = acc;
}

// ---------------- fused: xn = src (+ gv); [dstf = xn]; y = mod(ln(xn)) ----------------
__global__ void resid_ln(const float* __restrict__ src, const u16* __restrict__ gv,
                         const float* __restrict__ mod, int jshift, int jscale,
                         float* __restrict__ dstf, bf16* __restrict__ y) {
    int row = blockIdx.x;
    int b = row / TT, t = row % TT;
    int cz = (t >= HALF) ? 1 : 0;
    const float* mp = mod + (size_t)(b*2 + cz) * ND9;
    int tid = threadIdx.x;
    int w = tid >> 6, lane = tid & 63;
    int d0 = tid * 4;
    float4 s = *(const float4*)&src[(size_t)row*DD + d0];
    float v[4] = {s.x, s.y, s.z, s.w};
    if (gv) {
        ushort4 g = *(const ushort4*)&gv[(size_t)row*DD + d0];
        v[0] += bits2f(g.x); v[1] += bits2f(g.y); v[2] += bits2f(g.z); v[3] += bits2f(g.w);
    }
    if (dstf) *(float4*)&dstf[(size_t)row*DD + d0] = (float4){v[0], v[1], v[2], v[3]};
    float sum = v[0]+v[1]+v[2]+v[3];
    float ssq = v[0]*v[0]+v[1]*v[1]+v[2]*v[2]+v[3]*v[3];
    #pragma unroll
    for (int o = 32; o > 0; o >>= 1) {
        sum += __shfl_down(sum, o);
        ssq += __shfl_down(ssq, o);
    }
    __shared__ float wsum[4], wssq[4];
    if (lane == 0) { wsum[w] = sum; wssq[w] = ssq; }
    __syncthreads();
    float sall = (wsum[0]+wsum[1]) + (wsum[2]+wsum[3]);
    float qall = (wssq[0]+wssq[1]) + (wssq[2]+wssq[3]);
    float mean = sall * (1.f/DD);
    float var = qall * (1.f/DD) - mean*mean;
    float rstd = rsqrtf(var + 1e-6f);
    float4 sh = *(const float4*)&mp[jshift*DD + d0];
    float4 sc = *(const float4*)&mp[jscale*DD + d0];
    ushort4 o4;
    o4.x = fb((v[0]-mean)*rstd*(1.f+sc.x) + sh.x);
    o4.y = fb((v[1]-mean)*rstd*(1.f+sc.y) + sh.y);
    o4.z = fb((v[2]-mean)*rstd*(1.f+sc.z) + sh.z);
    o4.w = fb((v[3]-mean)*rstd*(1.f+sc.w) + sh.w);
    *(ushort4*)((u16*)y + (size_t)row*DD + d0) = o4;
}

// ---------------- W (KxN f32) -> Wt (NxK bf16 bits) ----------------
__global__ void transpose_w(const float* __restrict__ W, u16* __restrict__ Wt, int K, int N) {
    __shared__ float T[32][33];
    int n0 = blockIdx.x * 32, k0 = blockIdx.y * 32;
    int lx = threadIdx.x & 31, ly = threadIdx.x >> 5;
    #pragma unroll
    for (int i = 0; i < 4; ++i)
        T[ly + i*8][lx] = W[(size_t)(k0 + ly + i*8)*N + n0 + lx];
    __syncthreads();
    #pragma unroll
    for (int i = 0; i < 4; ++i) {
        int n = ly + i*8;
        Wt[(size_t)(n0 + n)*K + k0 + lx] = fb(T[lx][n]);
    }
}

// ---------------- V slice of qkv -> vt[bh*16+head][d][key] ----------------
__global__ void vtrans(const u16* __restrict__ qkv, u16* __restrict__ vt) {
    __shared__ u16 T[64][72];
    int kt = blockIdx.y;
    int gh = blockIdx.x;
    int tid = threadIdx.x;
    int key = tid >> 2, c8 = (tid & 3) * 16;
    const u16* src = qkv + (size_t)((gh >> 4)*1024 + kt*64 + key)*3072 + 2048 + (gh & 15)*64 + c8;
    *(uint4*)&T[key][c8]     = *(const uint4*)src;
    *(uint4*)&T[key][c8 + 8] = *(const uint4*)(src + 8);
    __syncthreads();
    int d = tid >> 2, kc = (tid & 3) * 16;
    u16 tmp[16];
    #pragma unroll
    for (int i = 0; i < 16; ++i) tmp[i] = T[kc + i][d];
    u16* dst = vt + ((size_t)gh*64 + d)*1024 + kt*64 + kc;
    *(uint4*)&dst[0] = *(const uint4*)&tmp[0];
    *(uint4*)&dst[8] = *(const uint4*)&tmp[8];
}

// ---------------- epilogue helper ----------------
// epi 0: plain bf16   epi 1: gelu bf16   epi 3: mod-gate bf16   epi 4: mod-gate + f32 residual add
// epi 5: mod-gate + f32 ATOMIC residual add (split-K partials)
__device__ __forceinline__ void epi_store(u16* out, int N, int mm, int n, float v,
                                          const float* mod, int jg, int epi) {
    if (epi == 0) {
        out[(size_t)mm*N + n] = fb(v);
    } else if (epi == 1) {
        float z = 0.7978845608028654f*(v + 0.044715f*v*v*v);
        out[(size_t)mm*N + n] = fb(v / (1.f + __expf(-2.f*z)));
    } else {
        int brow = mm / TT, tt2 = mm % TT;
        int cz = (tt2 >= HALF) ? 1 : 0;
        const float* mp = mod + (size_t)(brow*2 + cz)*ND9 + (size_t)jg*DD;
        if (epi == 3) {
            out[(size_t)mm*N + n] = fb(mp[n]*v);
        } else if (epi == 4) {
            float* of = (float*)out;
            size_t idx = (size_t)mm*N + n;
            of[idx] += mp[n]*v;
        } else {
            float* of = (float*)out;
            atomicAdd(&of[(size_t)mm*N + n], mp[n]*v);
        }
    }
}

// ---------------- MFMA GEMM 128x128 tile, BK=64, swizzled LDS + XCD swizzle ----------------
// launch_bounds(256,4): min 4 waves/SIMD = 4 blocks/CU resident (LDS 32KB*4=128<=160, VGPR<=128).
__global__ __launch_bounds__(256, 4) void gemm_mfma(
    const u16* __restrict__ A, const u16* __restrict__ Wt, const float* __restrict__ bias,
    u16* __restrict__ out, const float* __restrict__ mod, int jg,
    int K, int N, int epi)
{
    __shared__ u16 As[128*64];
    __shared__ u16 Bs[128*64];
    int tid = threadIdx.x;
    int w = tid >> 6, lane = tid & 63;
    int quad = lane >> 4, l16 = lane & 15;
    int bx, by; xcd_swz(bx, by);
    int m0 = by * 128;
    int n0 = bx * 128;
    int wr = (w & 1) * 64, wc = (w >> 1) * 64;

    f32x4 acc[4][4];
    #pragma unroll
    for (int i = 0; i < 4; ++i)
        #pragma unroll
        for (int j = 0; j < 4; ++j) acc[i][j] = (f32x4){0.f,0.f,0.f,0.f};

    const u16* Ag = A + (size_t)m0 * K;
    const u16* Bg = Wt + (size_t)n0 * K;
    int srow = lane >> 3;
    int scol = (((lane & 7) ^ ((lane >> 3) & 7))) * 8;
    int xsw = (l16 & 7);

    for (int k0 = 0; k0 < K; k0 += 64) {
        #pragma unroll
        for (int c = 0; c < 4; ++c) {
            int ch = w*4 + c;
            gl_lds16(Ag + (size_t)(ch*8 + srow)*K + k0 + scol, As + ch*512);
            gl_lds16(Bg + (size_t)(ch*8 + srow)*K + k0 + scol, Bs + ch*512);
        }
        __syncthreads();
        #pragma unroll
        for (int kk = 0; kk < 2; ++kk) {
            int pc = ((kk*4 + quad) ^ xsw) * 8;
            bf16x8 af[4], bfr[4];
            #pragma unroll
            for (int i = 0; i < 4; ++i) af[i] = *(const bf16x8*)&As[(wr + i*16 + l16)*64 + pc];
            #pragma unroll
            for (int j = 0; j < 4; ++j) bfr[j] = *(const bf16x8*)&Bs[(wc + j*16 + l16)*64 + pc];
            #pragma unroll
            for (int i = 0; i < 4; ++i)
                #pragma unroll
                for (int j = 0; j < 4; ++j)
                    acc[i][j] = __builtin_amdgcn_mfma_f32_16x16x32_bf16(af[i], bfr[j], acc[i][j], 0, 0, 0);
        }
        __syncthreads();
    }

    #pragma unroll
    for (int i = 0; i < 4; ++i)
        #pragma unroll
        for (int r = 0; r < 4; ++r) {
            int mm = m0 + wr + i*16 + quad*4 + r;
            #pragma unroll
            for (int j = 0; j < 4; ++j) {
                int n = n0 + wc + j*16 + l16;
                epi_store(out, N, mm, n, acc[i][j][r] + bias[n], mod, jg, epi);
            }
        }
}

// ---------------- MFMA GEMM 64x128 tile, BK=128 + XCD swizzle + optional split-K (z) --------
// launch_bounds(256,3): 3 blocks/CU max (LDS 48KB*3=144<=160). Klen = K-span per z-slice.
__global__ __launch_bounds__(256, 3) void gemm64_k128(
    const u16* __restrict__ A, const u16* __restrict__ Wt, const float* __restrict__ bias,
    u16* __restrict__ out, const float* __restrict__ mod, int jg,
    int K, int N, int epi, int Klen)
{
    __shared__ u16 As[2*64*64];      // 16 KB: [half][row][64]
    __shared__ u16 Bs[2*128*64];     // 32 KB
    int tid = threadIdx.x;
    int w = tid >> 6, lane = tid & 63;
    int quad = lane >> 4, l16 = lane & 15;
    int bx, by; xcd_swz(bx, by);
    int m0 = by * 64;
    int n0 = bx * 128;
    int koff = blockIdx.z * Klen;

    f32x4 acc[4][2];
    #pragma unroll
    for (int i = 0; i < 4; ++i)
        #pragma unroll
        for (int j = 0; j < 2; ++j) acc[i][j] = (f32x4){0.f,0.f,0.f,0.f};

    const u16* Ag = A + (size_t)m0 * K;
    const u16* Bg = Wt + (size_t)n0 * K;
    int srow = lane >> 3;
    int scol = (((lane & 7) ^ ((lane >> 3) & 7))) * 8;
    int xsw = (l16 & 7);

    for (int k0 = koff; k0 < koff + Klen; k0 += 128) {
        #pragma unroll
        for (int h = 0; h < 2; ++h) {
            #pragma unroll
            for (int c = 0; c < 2; ++c) {
                int ch = w*2 + c;
                gl_lds16(Ag + (size_t)(ch*8 + srow)*K + k0 + h*64 + scol, As + h*4096 + ch*512);
            }
            #pragma unroll
            for (int c = 0; c < 4; ++c) {
                int ch = w*4 + c;
                gl_lds16(Bg + (size_t)(ch*8 + srow)*K + k0 + h*64 + scol, Bs + h*8192 + ch*512);
            }
        }
        __syncthreads();
        #pragma unroll
        for (int kk = 0; kk < 4; ++kk) {
            int hh = kk >> 1;
            int pc = (((kk & 1)*4 + quad) ^ xsw) * 8;
            bf16x8 af[4], bfr[2];
            #pragma unroll
            for (int i = 0; i < 4; ++i) af[i] = *(const bf16x8*)&As[hh*4096 + (i*16 + l16)*64 + pc];
            #pragma unroll
            for (int j = 0; j < 2; ++j) bfr[j] = *(const bf16x8*)&Bs[hh*8192 + (w*32 + j*16 + l16)*64 + pc];
            #pragma unroll
            for (int i = 0; i < 4; ++i)
                #pragma unroll
                for (int j = 0; j < 2; ++j)
                    acc[i][j] = __builtin_amdgcn_mfma_f32_16x16x32_bf16(af[i], bfr[j], acc[i][j], 0, 0, 0);
        }
        __syncthreads();
    }

    float bsc = (koff == 0) ? 1.f : 0.f;               // bias folded into the k=0 split only
    #pragma unroll
    for (int i = 0; i < 4; ++i)
        #pragma unroll
        for (int r = 0; r < 4; ++r) {
            int mm = m0 + i*16 + quad*4 + r;
            #pragma unroll
            for (int j = 0; j < 2; ++j) {
                int n = n0 + w*32 + j*16 + l16;
                epi_store(out, N, mm, n, acc[i][j][r] + bsc*bias[n], mod, jg, epi);
            }
        }
}

// ---------------- MFMA flash attention (S^T trick, staged K/V, reg-prefetch) ----------------
__global__ __launch_bounds__(256) void attn_mfma(const u16* __restrict__ qkv,
                                                 const u16* __restrict__ vt,
                                                 u16* __restrict__ attn_out, int kv_swap) {
    __shared__ u16 Ks[64][72];       // [key][d]
    __shared__ u16 Vs[64][72];       // [d][key]
    __shared__ u16 Ps[4][16][72];    // per-wave P: [q=l16][key]
    int head = blockIdx.x, qt = blockIdx.y, bh = blockIdx.z;
    int kvbh = kv_swap ? (bh ^ 1) : bh;
    int tid = threadIdx.x;
    int w = tid >> 6, lane = tid & 63;
    int quad = lane >> 4, l16 = lane & 15;
    int qrow0 = bh*1024 + qt*64 + w*16;

    const u16* qp = qkv + (size_t)(qrow0 + l16)*3072 + head*64;
    bf16x8 qa0 = *(const bf16x8*)(qp + quad*8);        // Q[q=l16][d=quad*8+j]
    bf16x8 qa1 = *(const bf16x8*)(qp + 32 + quad*8);

    f32x4 oacc[4];
    #pragma unroll
    for (int i = 0; i < 4; ++i) oacc[i] = (f32x4){0.f,0.f,0.f,0.f};
    float mst = -3e38f, lst = 0.f;                     // running max (log2 domain) / denom per q

    int skey = tid >> 2, sc8 = (tid & 3) * 16;
    const u16* kbase = qkv + (size_t)(kvbh*1024 + skey)*3072 + 1024 + head*64 + sc8;
    const u16* vbase = vt + ((size_t)(kvbh*16 + head)*64 + skey)*1024 + sc8;

    uint4 kr0 = *(const uint4*)kbase;
    uint4 kr1 = *(const uint4*)(kbase + 8);
    uint4 vr0 = *(const uint4*)vbase;
    uint4 vr1 = *(const uint4*)(vbase + 8);

    const float SSC = 0.125f * 1.4426950408889634f;    // head-dim scale * log2(e)
    for (int kt = 0; kt < 16; ++kt) {
        __syncthreads();                               // previous tile fully consumed
        *(uint4*)&Ks[skey][sc8]     = kr0;
        *(uint4*)&Ks[skey][sc8 + 8] = kr1;
        *(uint4*)&Vs[skey][sc8]     = vr0;
        *(uint4*)&Vs[skey][sc8 + 8] = vr1;
        __syncthreads();
        if (kt < 15) {                                 // prefetch next tile into regs (hides under MFMA)
            const u16* kp = kbase + (size_t)(kt + 1)*64*3072;
            kr0 = *(const uint4*)kp;
            kr1 = *(const uint4*)(kp + 8);
            const u16* vp = vbase + (kt + 1)*64;
            vr0 = *(const uint4*)vp;
            vr1 = *(const uint4*)(vp + 8);
        }

        // S^T[key][q] = K·Q^T
        f32x4 sacc[4];
        #pragma unroll
        for (int nt = 0; nt < 4; ++nt) sacc[nt] = (f32x4){0.f,0.f,0.f,0.f};
        __builtin_amdgcn_s_setprio(1);
        #pragma unroll
        for (int nt = 0; nt < 4; ++nt) {
            bf16x8 kb0 = *(const bf16x8*)&Ks[nt*16 + l16][quad*8];
            bf16x8 kb1 = *(const bf16x8*)&Ks[nt*16 + l16][32 + quad*8];
            sacc[nt] = __builtin_amdgcn_mfma_f32_16x16x32_bf16(kb0, qa0, sacc[nt], 0, 0, 0);
            sacc[nt] = __builtin_amdgcn_mfma_f32_16x16x32_bf16(kb1, qa1, sacc[nt], 0, 0, 0);
        }
        __builtin_amdgcn_s_setprio(0);

        // softmax over keys (16 in-lane + cross-quad shfl) per q=l16, exp2 domain
        float sv[4][4];
        float tm = -3e38f;
        #pragma unroll
        for (int nt = 0; nt < 4; ++nt)
            #pragma unroll
            for (int r = 0; r < 4; ++r) {
                sv[nt][r] = sacc[nt][r] * SSC;
                tm = fmaxf(tm, sv[nt][r]);
            }
        tm = fmaxf(tm, __shfl_xor(tm, 16));
        tm = fmaxf(tm, __shfl_xor(tm, 32));
        if (!__all(tm <= mst + 11.5f)) {               // defer-max: rescale only on real growth
            float mnew = fmaxf(mst, tm);
            float alpha = fexp2(mst - mnew);
            lst *= alpha;
            #pragma unroll
            for (int dt = 0; dt < 4; ++dt)
                #pragma unroll
                for (int r = 0; r < 4; ++r) oacc[dt][r] *= alpha;
            mst = mnew;
        }
        float ls = 0.f;
        #pragma unroll
        for (int nt = 0; nt < 4; ++nt) {
            float p0 = fexp2(sv[nt][0] - mst), p1 = fexp2(sv[nt][1] - mst);
            float p2 = fexp2(sv[nt][2] - mst), p3 = fexp2(sv[nt][3] - mst);
            ls += (p0 + p1) + (p2 + p3);
            ushort4 pk = {fbh(p0), fbh(p1), fbh(p2), fbh(p3)};
            *(ushort4*)&Ps[w][l16][nt*16 + quad*4] = pk;
        }
        ls += __shfl_xor(ls, 16);
        ls += __shfl_xor(ls, 32);
        lst += ls;

        // O^T[d][q] += V^T·P^T
        bf16x8 pa0 = *(const bf16x8*)&Ps[w][l16][quad*8];
        bf16x8 pa1 = *(const bf16x8*)&Ps[w][l16][32 + quad*8];
        __builtin_amdgcn_s_setprio(1);
        #pragma unroll
        for (int dt = 0; dt < 4; ++dt) {
            bf16x8 vb0 = *(const bf16x8*)&Vs[dt*16 + l16][quad*8];
            bf16x8 vb1 = *(const bf16x8*)&Vs[dt*16 + l16][32 + quad*8];
            oacc[dt] = __builtin_amdgcn_mfma_f32_16x16x32_bf16(vb0, pa0, oacc[dt], 0, 0, 0);
            oacc[dt] = __builtin_amdgcn_mfma_f32_16x16x32_bf16(vb1, pa1, oacc[dt], 0, 0, 0);
        }
        __builtin_amdgcn_s_setprio(0);
    }
    float rl = 1.f / lst;
    #pragma unroll
    for (int dt = 0; dt < 4; ++dt) {
        ushort4 o4 = {fbh(oacc[dt][0]*rl), fbh(oacc[dt][1]*rl),
                      fbh(oacc[dt][2]*rl), fbh(oacc[dt][3]*rl)};
        *(ushort4*)&attn_out[(size_t)(qrow0 + l16)*DD + head*64 + dt*16 + quad*4] = o4;
    }
}

extern "C" void kernel_launch(void* const* d_in, const int* in_sizes, int n_in,
                              void* d_out, int out_size, void* d_ws, size_t ws_size,
                              hipStream_t stream) {
    const float* x          = (const float*)d_in[0];
    const float* c          = (const float*)d_in[1];
    const float* attn_qkv_w = (const float*)d_in[2];
    const float* attn_qkv_b = (const float*)d_in[3];
    const float* attn_proj_w= (const float*)d_in[4];
    const float* attn_proj_b= (const float*)d_in[5];
    const float* crs_qkv_w  = (const float*)d_in[6];
    const float* crs_qkv_b  = (const float*)d_in[7];
    const float* crs_proj_w = (const float*)d_in[8];
    const float* crs_proj_b = (const float*)d_in[9];
    const float* fc1_w      = (const float*)d_in[10];
    const float* fc1_b      = (const float*)d_in[11];
    const float* fc2_w      = (const float*)d_in[12];
    const float* fc2_b      = (const float*)d_in[13];
    const float* ada_w      = (const float*)d_in[14];
    const float* ada_b      = (const float*)d_in[15];
    float* out = (float*)d_out;     // f32 running residual

    // ws: mod 0.25 MB | R1 16 MB | Yr 8 MB | AOr 8 MB | BIGr 24 MB = 56.25 MB
    char* ws = (char*)d_ws;
    float* mod = (float*)ws;
    char* R1   = ws + (256u<<10);
    char* Yr   = R1 + (16u<<20);
    char* AOr  = Yr + (8u<<20);
    char* BIGr = AOr + (8u<<20);

    u16*   wt_a  = (u16*)R1;                   // 6 MB qkv weight T
    u16*   vt    = (u16*)(R1 + (8u<<20));      // 8 MB V-transpose
    bf16*  y     = (bf16*)Yr;                  // 8 MB ln output
    u16*   wt_p  = (u16*)Yr;                   // 2 MB proj weight T (y dead)
    u16*   attn_o= (u16*)AOr;                  // 8 MB
    u16*   big   = (u16*)BIGr;                 // 24 MB qkv
    u16*   gvB   = (u16*)BIGr;                 // 8 MB gated branch output (big dead)
    u16*   hstage= (u16*)AOr;                  // 32 MB fc1 out (AOr+BIGr contiguous)
    u16*   fc1_t = (u16*)R1;                   // 8 MB
    u16*   fc2_t = (u16*)(R1 + (8u<<20));      // 8 MB
    float* apart = (float*)BIGr;               // 2.4 MB ada partials (pre-MSA only)

    ada_part<<<dim3(9, 16), 256, 0, stream>>>(c, ada_w, apart);
    ada_reduce<<<36, 256, 0, stream>>>(apart, ada_b, mod);

    // ================= MSA =================
    transpose_w<<<dim3(3*DD/32, DD/32), 256, 0, stream>>>(attn_qkv_w, wt_a, DD, 3*DD);
    // fused x-copy: read x, write residual copy to out, produce y = mod(ln(x))
    resid_ln<<<ROWS, 256, 0, stream>>>(x, nullptr, mod, 0, 1, out, y);
    gemm_mfma<<<dim3(3*DD/128, ROWS/128), 256, 0, stream>>>((const u16*)y, wt_a, attn_qkv_b,
                                                            big, nullptr, 0, DD, 3*DD, 0);
    vtrans<<<dim3(64, 16), 256, 0, stream>>>(big, vt);
    attn_mfma<<<dim3(NH, 16, 4), 256, 0, stream>>>(big, vt, attn_o, 0);
    transpose_w<<<dim3(DD/32, DD/32), 256, 0, stream>>>(attn_proj_w, wt_p, DD, DD);
    gemm64_k128<<<dim3(DD/128, ROWS/64), 256, 0, stream>>>(attn_o, wt_p, attn_proj_b,
                                                           gvB, mod, 2, DD, DD, 3, DD);
    // y = mod(ln(out + gvB)) for MCA; running residual (out) unchanged per reference
    resid_ln<<<ROWS, 256, 0, stream>>>(out, gvB, mod, 3, 4, nullptr, y);

    // ================= MCA =================
    transpose_w<<<dim3(3*DD/32, DD/32), 256, 0, stream>>>(crs_qkv_w, wt_a, DD, 3*DD);
    gemm_mfma<<<dim3(3*DD/128, ROWS/128), 256, 0, stream>>>((const u16*)y, wt_a, crs_qkv_b,
                                                            big, nullptr, 0, DD, 3*DD, 0);
    vtrans<<<dim3(64, 16), 256, 0, stream>>>(big, vt);
    attn_mfma<<<dim3(NH, 16, 4), 256, 0, stream>>>(big, vt, attn_o, 1);
    transpose_w<<<dim3(DD/32, DD/32), 256, 0, stream>>>(crs_proj_w, wt_p, DD, DD);
    gemm64_k128<<<dim3(DD/128, ROWS/64), 256, 0, stream>>>(attn_o, wt_p, crs_proj_b,
                                                           gvB, mod, 5, DD, DD, 3, DD);
    // out += gvB (store), y = mod(ln(out)) for MLP
    resid_ln<<<ROWS, 256, 0, stream>>>(out, gvB, mod, 6, 7, out, y);

    // ================= MLP =================
    transpose_w<<<dim3(DHID/32, DD/32), 256, 0, stream>>>(fc1_w, fc1_t, DD, DHID);
    transpose_w<<<dim3(DD/32, DHID/32), 256, 0, stream>>>(fc2_w, fc2_t, DHID, DD);
    gemm_mfma<<<dim3(DHID/128, ROWS/128), 256, 0, stream>>>((const u16*)y, fc1_t, fc1_b,
                                                            hstage, nullptr, 0, DD, DHID, 1);
    // fc2: split-K=2 (grid z), ATOMIC f32 mod-gated accumulation into out (epi=5).
    // 1024 blocks (~3/CU resident) vs 512 before; bias folded into the k=0 split.
    gemm64_k128<<<dim3(DD/128, ROWS/64, 2), 256, 0, stream>>>(hstage, fc2_t, fc2_b,
                                                              (u16*)out, mod, 8, DHID, DD, 5, DHID/2);
}

// Round 12
// 505.502 us; speedup vs baseline: 1.1032x; 1.0772x over previous
//
#include <hip/hip_runtime.h>
#include <hip/hip_bf16.h>

#define BB 2
#define TT 2048
#define DD 1024
#define NH 16
#define HALF 1024
#define DHID 4096
#define ND9 9216
#define ROWS (BB*TT)

using bf16 = __hip_bfloat16;
typedef short bf16x8 __attribute__((ext_vector_type(8)));
typedef float f32x4 __attribute__((ext_vector_type(4)));
typedef unsigned short u16;

__device__ __forceinline__ float bits2f(u16 b){ return __uint_as_float(((unsigned)b) << 16); }
__device__ __forceinline__ u16 fb(float v){              // float -> bf16 bits (RNE, bit-twiddle)
    unsigned u = __float_as_uint(v);
    u += 0x7fffu + ((u >> 16) & 1u);
    return (u16)(u >> 16);
}
__device__ __forceinline__ u16 fbh(float v){             // via cast: compiler fuses pairs to v_cvt_pk_bf16_f32
    bf16 b = __float2bfloat16(v);
    return *(u16*)&b;
}
__device__ __forceinline__ float fexp2(float x){
#if __has_builtin(__builtin_amdgcn_exp2f)
    return __builtin_amdgcn_exp2f(x);
#else
    return exp2f(x);
#endif
}
__device__ __forceinline__ void gl_lds16(const u16* g, u16* l) {
    __builtin_amdgcn_global_load_lds(
        (const __attribute__((address_space(1))) unsigned int*)g,
        (__attribute__((address_space(3))) unsigned int*)l, 16, 0, 0);
}
// XCD-chunked bijective block remap (T1): blocks sharing an operand panel land on one XCD.
// Requires nwg % 8 == 0 (all GEMM grids here satisfy this).
__device__ __forceinline__ void xcd_swz(int& bx, int& by) {
    int gx = gridDim.x;
    int nwg = gx * gridDim.y;
    int flat = blockIdx.y * gx + blockIdx.x;
    int swz = (flat & 7) * (nwg >> 3) + (flat >> 3);
    bx = swz % gx;
    by = swz / gx;
}

// ---------------- ada stage 1: partial[s][r][n] over 32-k slices (288 blocks: all CUs) -------
__global__ void ada_part(const float* __restrict__ c, const float* __restrict__ ada_w,
                         float* __restrict__ part) {
    __shared__ float sc_[4][32];
    int s = blockIdx.y;
    int k0 = s * 32;
    int n0 = blockIdx.x * 1024 + threadIdx.x * 4;
    if (threadIdx.x < 128) {
        int r = threadIdx.x >> 5, k = threadIdx.x & 31;
        float v = c[r*DD + k0 + k];
        sc_[r][k] = v / (1.f + __expf(-v));
    }
    __syncthreads();
    float4 a0 = {0,0,0,0}, a1 = {0,0,0,0}, a2 = {0,0,0,0}, a3 = {0,0,0,0};
    for (int k = 0; k < 32; ++k) {
        float4 wv = *(const float4*)&ada_w[(size_t)(k0 + k)*ND9 + n0];
        float s0 = sc_[0][k], s1 = sc_[1][k], s2 = sc_[2][k], s3 = sc_[3][k];
        a0.x += s0*wv.x; a0.y += s0*wv.y; a0.z += s0*wv.z; a0.w += s0*wv.w;
        a1.x += s1*wv.x; a1.y += s1*wv.y; a1.z += s1*wv.z; a1.w += s1*wv.w;
        a2.x += s2*wv.x; a2.y += s2*wv.y; a2.z += s2*wv.z; a2.w += s2*wv.w;
        a3.x += s3*wv.x; a3.y += s3*wv.y; a3.z += s3*wv.z; a3.w += s3*wv.w;
    }
    *(float4*)&part[((size_t)(s*4 + 0))*ND9 + n0] = a0;
    *(float4*)&part[((size_t)(s*4 + 1))*ND9 + n0] = a1;
    *(float4*)&part[((size_t)(s*4 + 2))*ND9 + n0] = a2;
    *(float4*)&part[((size_t)(s*4 + 3))*ND9 + n0] = a3;
}

// ---------------- ada stage 2 ----------------
__global__ void ada_reduce(const float* __restrict__ part, const float* __restrict__ ada_b,
                           float* __restrict__ mod) {
    int g = blockIdx.x * 1024 + threadIdx.x * 4;
    int r = g / ND9, n = g - r*ND9;
    float4 acc = *(const float4*)&ada_b[n];
    #pragma unroll
    for (int s = 0; s < 32; ++s) {
        float4 p = *(const float4*)&part[((size_t)(s*4 + r))*ND9 + n];
        acc.x += p.x; acc.y += p.y; acc.z += p.z; acc.w += p.w;
    }
    *(float4*)&mod[(size_t)r*ND9 + n] = acc;
}

// ---------------- fused: xn = src (+ gv); [dstf = xn]; y = mod(ln(xn)) ----------------
__global__ void resid_ln(const float* __restrict__ src, const u16* __restrict__ gv,
                         const float* __restrict__ mod, int jshift, int jscale,
                         float* __restrict__ dstf, bf16* __restrict__ y) {
    int row = blockIdx.x;
    int b = row / TT, t = row % TT;
    int cz = (t >= HALF) ? 1 : 0;
    const float* mp = mod + (size_t)(b*2 + cz) * ND9;
    int tid = threadIdx.x;
    int w = tid >> 6, lane = tid & 63;
    int d0 = tid * 4;
    float4 s = *(const float4*)&src[(size_t)row*DD + d0];
    float v[4] = {s.x, s.y, s.z, s.w};
    if (gv) {
        ushort4 g = *(const ushort4*)&gv[(size_t)row*DD + d0];
        v[0] += bits2f(g.x); v[1] += bits2f(g.y); v[2] += bits2f(g.z); v[3] += bits2f(g.w);
    }
    if (dstf) *(float4*)&dstf[(size_t)row*DD + d0] = (float4){v[0], v[1], v[2], v[3]};
    float sum = v[0]+v[1]+v[2]+v[3];
    float ssq = v[0]*v[0]+v[1]*v[1]+v[2]*v[2]+v[3]*v[3];
    #pragma unroll
    for (int o = 32; o > 0; o >>= 1) {
        sum += __shfl_down(sum, o);
        ssq += __shfl_down(ssq, o);
    }
    __shared__ float wsum[4], wssq[4];
    if (lane == 0) { wsum[w] = sum; wssq[w] = ssq; }
    __syncthreads();
    float sall = (wsum[0]+wsum[1]) + (wsum[2]+wsum[3]);
    float qall = (wssq[0]+wssq[1]) + (wssq[2]+wssq[3]);
    float mean = sall * (1.f/DD);
    float var = qall * (1.f/DD) - mean*mean;
    float rstd = rsqrtf(var + 1e-6f);
    float4 sh = *(const float4*)&mp[jshift*DD + d0];
    float4 sc = *(const float4*)&mp[jscale*DD + d0];
    ushort4 o4;
    o4.x = fb((v[0]-mean)*rstd*(1.f+sc.x) + sh.x);
    o4.y = fb((v[1]-mean)*rstd*(1.f+sc.y) + sh.y);
    o4.z = fb((v[2]-mean)*rstd*(1.f+sc.z) + sh.z);
    o4.w = fb((v[3]-mean)*rstd*(1.f+sc.w) + sh.w);
    *(ushort4*)((u16*)y + (size_t)row*DD + d0) = o4;
}

// ---------------- W (KxN f32) -> Wt (NxK bf16 bits) ----------------
__global__ void transpose_w(const float* __restrict__ W, u16* __restrict__ Wt, int K, int N) {
    __shared__ float T[32][33];
    int n0 = blockIdx.x * 32, k0 = blockIdx.y * 32;
    int lx = threadIdx.x & 31, ly = threadIdx.x >> 5;
    #pragma unroll
    for (int i = 0; i < 4; ++i)
        T[ly + i*8][lx] = W[(size_t)(k0 + ly + i*8)*N + n0 + lx];
    __syncthreads();
    #pragma unroll
    for (int i = 0; i < 4; ++i) {
        int n = ly + i*8;
        Wt[(size_t)(n0 + n)*K + k0 + lx] = fb(T[lx][n]);
    }
}

// ---------------- V slice of qkv -> vt[bh*16+head][d][key] ----------------
__global__ void vtrans(const u16* __restrict__ qkv, u16* __restrict__ vt) {
    __shared__ u16 T[64][72];
    int kt = blockIdx.y;
    int gh = blockIdx.x;
    int tid = threadIdx.x;
    int key = tid >> 2, c8 = (tid & 3) * 16;
    const u16* src = qkv + (size_t)((gh >> 4)*1024 + kt*64 + key)*3072 + 2048 + (gh & 15)*64 + c8;
    *(uint4*)&T[key][c8]     = *(const uint4*)src;
    *(uint4*)&T[key][c8 + 8] = *(const uint4*)(src + 8);
    __syncthreads();
    int d = tid >> 2, kc = (tid & 3) * 16;
    u16 tmp[16];
    #pragma unroll
    for (int i = 0; i < 16; ++i) tmp[i] = T[kc + i][d];
    u16* dst = vt + ((size_t)gh*64 + d)*1024 + kt*64 + kc;
    *(uint4*)&dst[0] = *(const uint4*)&tmp[0];
    *(uint4*)&dst[8] = *(const uint4*)&tmp[8];
}

// ---------------- epilogue helper ----------------
// epi 0: plain bf16   epi 1: gelu bf16   epi 3: mod-gate bf16   epi 4: mod-gate + f32 residual add (in place)
__device__ __forceinline__ void epi_store(u16* out, int N, int mm, int n, float v,
                                          const float* mod, int jg, int epi) {
    if (epi == 0) {
        out[(size_t)mm*N + n] = fb(v);
    } else if (epi == 1) {
        float z = 0.7978845608028654f*(v + 0.044715f*v*v*v);
        out[(size_t)mm*N + n] = fb(v / (1.f + __expf(-2.f*z)));
    } else {
        int brow = mm / TT, tt2 = mm % TT;
        int cz = (tt2 >= HALF) ? 1 : 0;
        const float* mp = mod + (size_t)(brow*2 + cz)*ND9 + (size_t)jg*DD;
        if (epi == 3) {
            out[(size_t)mm*N + n] = fb(mp[n]*v);
        } else {
            float* of = (float*)out;
            size_t idx = (size_t)mm*N + n;
            of[idx] += mp[n]*v;
        }
    }
}

// ---------------- MFMA GEMM 128x128 tile, BK=64, swizzled LDS + XCD swizzle ----------------
__global__ __launch_bounds__(256, 2) void gemm_mfma(
    const u16* __restrict__ A, const u16* __restrict__ Wt, const float* __restrict__ bias,
    u16* __restrict__ out, const float* __restrict__ mod, int jg,
    int K, int N, int epi)
{
    __shared__ u16 As[128*64];
    __shared__ u16 Bs[128*64];
    int tid = threadIdx.x;
    int w = tid >> 6, lane = tid & 63;
    int quad = lane >> 4, l16 = lane & 15;
    int bx, by; xcd_swz(bx, by);
    int m0 = by * 128;
    int n0 = bx * 128;
    int wr = (w & 1) * 64, wc = (w >> 1) * 64;

    f32x4 acc[4][4];
    #pragma unroll
    for (int i = 0; i < 4; ++i)
        #pragma unroll
        for (int j = 0; j < 4; ++j) acc[i][j] = (f32x4){0.f,0.f,0.f,0.f};

    const u16* Ag = A + (size_t)m0 * K;
    const u16* Bg = Wt + (size_t)n0 * K;
    int srow = lane >> 3;
    int scol = (((lane & 7) ^ ((lane >> 3) & 7))) * 8;
    int xsw = (l16 & 7);

    for (int k0 = 0; k0 < K; k0 += 64) {
        #pragma unroll
        for (int c = 0; c < 4; ++c) {
            int ch = w*4 + c;
            gl_lds16(Ag + (size_t)(ch*8 + srow)*K + k0 + scol, As + ch*512);
            gl_lds16(Bg + (size_t)(ch*8 + srow)*K + k0 + scol, Bs + ch*512);
        }
        __syncthreads();
        #pragma unroll
        for (int kk = 0; kk < 2; ++kk) {
            int pc = ((kk*4 + quad) ^ xsw) * 8;
            bf16x8 af[4], bfr[4];
            #pragma unroll
            for (int i = 0; i < 4; ++i) af[i] = *(const bf16x8*)&As[(wr + i*16 + l16)*64 + pc];
            #pragma unroll
            for (int j = 0; j < 4; ++j) bfr[j] = *(const bf16x8*)&Bs[(wc + j*16 + l16)*64 + pc];
            #pragma unroll
            for (int i = 0; i < 4; ++i)
                #pragma unroll
                for (int j = 0; j < 4; ++j)
                    acc[i][j] = __builtin_amdgcn_mfma_f32_16x16x32_bf16(af[i], bfr[j], acc[i][j], 0, 0, 0);
        }
        __syncthreads();
    }

    #pragma unroll
    for (int i = 0; i < 4; ++i)
        #pragma unroll
        for (int r = 0; r < 4; ++r) {
            int mm = m0 + wr + i*16 + quad*4 + r;
            #pragma unroll
            for (int j = 0; j < 4; ++j) {
                int n = n0 + wc + j*16 + l16;
                epi_store(out, N, mm, n, acc[i][j][r] + bias[n], mod, jg, epi);
            }
        }
}

// ---------------- MFMA GEMM 64x128 tile, BK=128 + XCD swizzle ----------------
// LDS stored as two 64-col planes per operand: plane h covers k-cols [h*64, h*64+64).
__global__ __launch_bounds__(256, 2) void gemm64_k128(
    const u16* __restrict__ A, const u16* __restrict__ Wt, const float* __restrict__ bias,
    u16* __restrict__ out, const float* __restrict__ mod, int jg,
    int K, int N, int epi)
{
    __shared__ u16 As[2*64*64];      // 16 KB: [half][row][64]
    __shared__ u16 Bs[2*128*64];     // 32 KB
    int tid = threadIdx.x;
    int w = tid >> 6, lane = tid & 63;
    int quad = lane >> 4, l16 = lane & 15;
    int bx, by; xcd_swz(bx, by);
    int m0 = by * 64;
    int n0 = bx * 128;

    f32x4 acc[4][2];
    #pragma unroll
    for (int i = 0; i < 4; ++i)
        #pragma unroll
        for (int j = 0; j < 2; ++j) acc[i][j] = (f32x4){0.f,0.f,0.f,0.f};

    const u16* Ag = A + (size_t)m0 * K;
    const u16* Bg = Wt + (size_t)n0 * K;
    int srow = lane >> 3;
    int scol = (((lane & 7) ^ ((lane >> 3) & 7))) * 8;
    int xsw = (l16 & 7);

    for (int k0 = 0; k0 < K; k0 += 128) {
        #pragma unroll
        for (int h = 0; h < 2; ++h) {
            #pragma unroll
            for (int c = 0; c < 2; ++c) {
                int ch = w*2 + c;
                gl_lds16(Ag + (size_t)(ch*8 + srow)*K + k0 + h*64 + scol, As + h*4096 + ch*512);
            }
            #pragma unroll
            for (int c = 0; c < 4; ++c) {
                int ch = w*4 + c;
                gl_lds16(Bg + (size_t)(ch*8 + srow)*K + k0 + h*64 + scol, Bs + h*8192 + ch*512);
            }
        }
        __syncthreads();
        #pragma unroll
        for (int kk = 0; kk < 4; ++kk) {
            int hh = kk >> 1;
            int pc = (((kk & 1)*4 + quad) ^ xsw) * 8;
            bf16x8 af[4], bfr[2];
            #pragma unroll
            for (int i = 0; i < 4; ++i) af[i] = *(const bf16x8*)&As[hh*4096 + (i*16 + l16)*64 + pc];
            #pragma unroll
            for (int j = 0; j < 2; ++j) bfr[j] = *(const bf16x8*)&Bs[hh*8192 + (w*32 + j*16 + l16)*64 + pc];
            #pragma unroll
            for (int i = 0; i < 4; ++i)
                #pragma unroll
                for (int j = 0; j < 2; ++j)
                    acc[i][j] = __builtin_amdgcn_mfma_f32_16x16x32_bf16(af[i], bfr[j], acc[i][j], 0, 0, 0);
        }
        __syncthreads();
    }

    #pragma unroll
    for (int i = 0; i < 4; ++i)
        #pragma unroll
        for (int r = 0; r < 4; ++r) {
            int mm = m0 + i*16 + quad*4 + r;
            #pragma unroll
            for (int j = 0; j < 2; ++j) {
                int n = n0 + w*32 + j*16 + l16;
                epi_store(out, N, mm, n, acc[i][j][r] + bias[n], mod, jg, epi);
            }
        }
}

// ---------------- MFMA flash attention (S^T trick, staged K/V, reg-prefetch) ----------------
// grid (NH, 16 qtiles, 4 bh) — head fastest: all 16 qt-blocks of a head have flat%8 == head%8,
// so a head's K/V re-reads are already XCD-local. Softmax: exp2-domain + defer-max + cvt_pk.
__global__ __launch_bounds__(256) void attn_mfma(const u16* __restrict__ qkv,
                                                 const u16* __restrict__ vt,
                                                 u16* __restrict__ attn_out, int kv_swap) {
    __shared__ u16 Ks[64][72];       // [key][d]
    __shared__ u16 Vs[64][72];       // [d][key]
    __shared__ u16 Ps[4][16][72];    // per-wave P: [q=l16][key]
    int head = blockIdx.x, qt = blockIdx.y, bh = blockIdx.z;
    int kvbh = kv_swap ? (bh ^ 1) : bh;
    int tid = threadIdx.x;
    int w = tid >> 6, lane = tid & 63;
    int quad = lane >> 4, l16 = lane & 15;
    int qrow0 = bh*1024 + qt*64 + w*16;

    const u16* qp = qkv + (size_t)(qrow0 + l16)*3072 + head*64;
    bf16x8 qa0 = *(const bf16x8*)(qp + quad*8);        // Q[q=l16][d=quad*8+j]
    bf16x8 qa1 = *(const bf16x8*)(qp + 32 + quad*8);

    f32x4 oacc[4];
    #pragma unroll
    for (int i = 0; i < 4; ++i) oacc[i] = (f32x4){0.f,0.f,0.f,0.f};
    float mst = -3e38f, lst = 0.f;                     // running max (log2 domain) / denom per q

    int skey = tid >> 2, sc8 = (tid & 3) * 16;
    const u16* kbase = qkv + (size_t)(kvbh*1024 + skey)*3072 + 1024 + head*64 + sc8;
    const u16* vbase = vt + ((size_t)(kvbh*16 + head)*64 + skey)*1024 + sc8;

    uint4 kr0 = *(const uint4*)kbase;
    uint4 kr1 = *(const uint4*)(kbase + 8);
    uint4 vr0 = *(const uint4*)vbase;
    uint4 vr1 = *(const uint4*)(vbase + 8);

    const float SSC = 0.125f * 1.4426950408889634f;    // head-dim scale * log2(e)
    for (int kt = 0; kt < 16; ++kt) {
        __syncthreads();                               // previous tile fully consumed
        *(uint4*)&Ks[skey][sc8]     = kr0;
        *(uint4*)&Ks[skey][sc8 + 8] = kr1;
        *(uint4*)&Vs[skey][sc8]     = vr0;
        *(uint4*)&Vs[skey][sc8 + 8] = vr1;
        __syncthreads();
        if (kt < 15) {                                 // prefetch next tile into regs (hides under MFMA)
            const u16* kp = kbase + (size_t)(kt + 1)*64*3072;
            kr0 = *(const uint4*)kp;
            kr1 = *(const uint4*)(kp + 8);
            const u16* vp = vbase + (kt + 1)*64;
            vr0 = *(const uint4*)vp;
            vr1 = *(const uint4*)(vp + 8);
        }

        // S^T[key][q] = K·Q^T
        f32x4 sacc[4];
        #pragma unroll
        for (int nt = 0; nt < 4; ++nt) sacc[nt] = (f32x4){0.f,0.f,0.f,0.f};
        __builtin_amdgcn_s_setprio(1);
        #pragma unroll
        for (int nt = 0; nt < 4; ++nt) {
            bf16x8 kb0 = *(const bf16x8*)&Ks[nt*16 + l16][quad*8];
            bf16x8 kb1 = *(const bf16x8*)&Ks[nt*16 + l16][32 + quad*8];
            sacc[nt] = __builtin_amdgcn_mfma_f32_16x16x32_bf16(kb0, qa0, sacc[nt], 0, 0, 0);
            sacc[nt] = __builtin_amdgcn_mfma_f32_16x16x32_bf16(kb1, qa1, sacc[nt], 0, 0, 0);
        }
        __builtin_amdgcn_s_setprio(0);

        // softmax over keys (16 in-lane + cross-quad shfl) per q=l16, exp2 domain
        float sv[4][4];
        float tm = -3e38f;
        #pragma unroll
        for (int nt = 0; nt < 4; ++nt)
            #pragma unroll
            for (int r = 0; r < 4; ++r) {
                sv[nt][r] = sacc[nt][r] * SSC;
                tm = fmaxf(tm, sv[nt][r]);
            }
        tm = fmaxf(tm, __shfl_xor(tm, 16));
        tm = fmaxf(tm, __shfl_xor(tm, 32));
        if (!__all(tm <= mst + 11.5f)) {               // defer-max: rescale only on real growth
            float mnew = fmaxf(mst, tm);
            float alpha = fexp2(mst - mnew);
            lst *= alpha;
            #pragma unroll
            for (int dt = 0; dt < 4; ++dt)
                #pragma unroll
                for (int r = 0; r < 4; ++r) oacc[dt][r] *= alpha;
            mst = mnew;
        }
        float ls = 0.f;
        #pragma unroll
        for (int nt = 0; nt < 4; ++nt) {
            float p0 = fexp2(sv[nt][0] - mst), p1 = fexp2(sv[nt][1] - mst);
            float p2 = fexp2(sv[nt][2] - mst), p3 = fexp2(sv[nt][3] - mst);
            ls += (p0 + p1) + (p2 + p3);
            ushort4 pk = {fbh(p0), fbh(p1), fbh(p2), fbh(p3)};
            *(ushort4*)&Ps[w][l16][nt*16 + quad*4] = pk;
        }
        ls += __shfl_xor(ls, 16);
        ls += __shfl_xor(ls, 32);
        lst += ls;

        // O^T[d][q] += V^T·P^T
        bf16x8 pa0 = *(const bf16x8*)&Ps[w][l16][quad*8];
        bf16x8 pa1 = *(const bf16x8*)&Ps[w][l16][32 + quad*8];
        __builtin_amdgcn_s_setprio(1);
        #pragma unroll
        for (int dt = 0; dt < 4; ++dt) {
            bf16x8 vb0 = *(const bf16x8*)&Vs[dt*16 + l16][quad*8];
            bf16x8 vb1 = *(const bf16x8*)&Vs[dt*16 + l16][32 + quad*8];
            oacc[dt] = __builtin_amdgcn_mfma_f32_16x16x32_bf16(vb0, pa0, oacc[dt], 0, 0, 0);
            oacc[dt] = __builtin_amdgcn_mfma_f32_16x16x32_bf16(vb1, pa1, oacc[dt], 0, 0, 0);
        }
        __builtin_amdgcn_s_setprio(0);
    }
    float rl = 1.f / lst;
    #pragma unroll
    for (int dt = 0; dt < 4; ++dt) {
        ushort4 o4 = {fbh(oacc[dt][0]*rl), fbh(oacc[dt][1]*rl),
                      fbh(oacc[dt][2]*rl), fbh(oacc[dt][3]*rl)};
        *(ushort4*)&attn_out[(size_t)(qrow0 + l16)*DD + head*64 + dt*16 + quad*4] = o4;
    }
}

extern "C" void kernel_launch(void* const* d_in, const int* in_sizes, int n_in,
                              void* d_out, int out_size, void* d_ws, size_t ws_size,
                              hipStream_t stream) {
    const float* x          = (const float*)d_in[0];
    const float* c          = (const float*)d_in[1];
    const float* attn_qkv_w = (const float*)d_in[2];
    const float* attn_qkv_b = (const float*)d_in[3];
    const float* attn_proj_w= (const float*)d_in[4];
    const float* attn_proj_b= (const float*)d_in[5];
    const float* crs_qkv_w  = (const float*)d_in[6];
    const float* crs_qkv_b  = (const float*)d_in[7];
    const float* crs_proj_w = (const float*)d_in[8];
    const float* crs_proj_b = (const float*)d_in[9];
    const float* fc1_w      = (const float*)d_in[10];
    const float* fc1_b      = (const float*)d_in[11];
    const float* fc2_w      = (const float*)d_in[12];
    const float* fc2_b      = (const float*)d_in[13];
    const float* ada_w      = (const float*)d_in[14];
    const float* ada_b      = (const float*)d_in[15];
    float* out = (float*)d_out;     // f32 running residual

    // ws: mod 0.25 MB | R1 16 MB | Yr 8 MB | AOr 8 MB | BIGr 24 MB = 56.25 MB
    char* ws = (char*)d_ws;
    float* mod = (float*)ws;
    char* R1   = ws + (256u<<10);
    char* Yr   = R1 + (16u<<20);
    char* AOr  = Yr + (8u<<20);
    char* BIGr = AOr + (8u<<20);

    u16*   wt_a  = (u16*)R1;                   // 6 MB qkv weight T
    u16*   vt    = (u16*)(R1 + (8u<<20));      // 8 MB V-transpose
    bf16*  y     = (bf16*)Yr;                  // 8 MB ln output
    u16*   wt_p  = (u16*)Yr;                   // 2 MB proj weight T (y dead)
    u16*   attn_o= (u16*)AOr;                  // 8 MB
    u16*   big   = (u16*)BIGr;                 // 24 MB qkv
    u16*   gvB   = (u16*)BIGr;                 // 8 MB gated branch output (big dead)
    u16*   hstage= (u16*)AOr;                  // 32 MB fc1 out (AOr+BIGr contiguous)
    u16*   fc1_t = (u16*)R1;                   // 8 MB
    u16*   fc2_t = (u16*)(R1 + (8u<<20));      // 8 MB
    float* apart = (float*)BIGr;               // 4.7 MB ada partials (pre-MSA only)

    ada_part<<<dim3(9, 32), 256, 0, stream>>>(c, ada_w, apart);
    ada_reduce<<<36, 256, 0, stream>>>(apart, ada_b, mod);

    // ================= MSA =================
    transpose_w<<<dim3(3*DD/32, DD/32), 256, 0, stream>>>(attn_qkv_w, wt_a, DD, 3*DD);
    // fused x-copy: read x, write residual copy to out, produce y = mod(ln(x))
    resid_ln<<<ROWS, 256, 0, stream>>>(x, nullptr, mod, 0, 1, out, y);
    gemm_mfma<<<dim3(3*DD/128, ROWS/128), 256, 0, stream>>>((const u16*)y, wt_a, attn_qkv_b,
                                                            big, nullptr, 0, DD, 3*DD, 0);
    vtrans<<<dim3(64, 16), 256, 0, stream>>>(big, vt);
    attn_mfma<<<dim3(NH, 16, 4), 256, 0, stream>>>(big, vt, attn_o, 0);
    transpose_w<<<dim3(DD/32, DD/32), 256, 0, stream>>>(attn_proj_w, wt_p, DD, DD);
    gemm64_k128<<<dim3(DD/128, ROWS/64), 256, 0, stream>>>(attn_o, wt_p, attn_proj_b,
                                                           gvB, mod, 2, DD, DD, 3);
    // y = mod(ln(out + gvB)) for MCA; running residual (out) unchanged per reference
    resid_ln<<<ROWS, 256, 0, stream>>>(out, gvB, mod, 3, 4, nullptr, y);

    // ================= MCA =================
    transpose_w<<<dim3(3*DD/32, DD/32), 256, 0, stream>>>(crs_qkv_w, wt_a, DD, 3*DD);
    gemm_mfma<<<dim3(3*DD/128, ROWS/128), 256, 0, stream>>>((const u16*)y, wt_a, crs_qkv_b,
                                                            big, nullptr, 0, DD, 3*DD, 0);
    vtrans<<<dim3(64, 16), 256, 0, stream>>>(big, vt);
    attn_mfma<<<dim3(NH, 16, 4), 256, 0, stream>>>(big, vt, attn_o, 1);
    transpose_w<<<dim3(DD/32, DD/32), 256, 0, stream>>>(crs_proj_w, wt_p, DD, DD);
    gemm64_k128<<<dim3(DD/128, ROWS/64), 256, 0, stream>>>(attn_o, wt_p, crs_proj_b,
                                                           gvB, mod, 5, DD, DD, 3);
    // out += gvB (store), y = mod(ln(out)) for MLP
    resid_ln<<<ROWS, 256, 0, stream>>>(out, gvB, mod, 6, 7, out, y);

    // ================= MLP =================
    transpose_w<<<dim3(DHID/32, DD/32), 256, 0, stream>>>(fc1_w, fc1_t, DD, DHID);
    transpose_w<<<dim3(DD/32, DHID/32), 256, 0, stream>>>(fc2_w, fc2_t, DHID, DD);
    gemm_mfma<<<dim3(DHID/128, ROWS/128), 256, 0, stream>>>((const u16*)y, fc1_t, fc1_b,
                                                            hstage, nullptr, 0, DD, DHID, 1);
    // fc2 with fused mod-gate + f32 residual add directly into out (epi=4)
    gemm64_k128<<<dim3(DD/128, ROWS/64), 256, 0, stream>>>(hstage, fc2_t, fc2_b,
                                                           (u16*)out, mod, 8, DHID, DD, 4);
}